// Round 2
// 190.259 us; speedup vs baseline: 1.0331x; 1.0331x over previous
//
#include <hip/hip_runtime.h>

// SaltAndPepper: out = where(mask==0, 0, where(mask==1, 1, image))
// image: (32,3,512,512) f32, mask: (32,1,512,512) i32 broadcast over C.
//
// Experiment ledger (kernel-dispatch time via rocprof):
//   R2  1 float4-group/thread, linear streams        63.5-66 us  <-- best
//   R4  unroll x4 + nontemporal stores               70.5 us  regress (confounded)
//   R5  persistent grid (2048 blocks, 12 grp/thread) 75.5 us  regress (+50% FETCH)
//   R6  mask-once, 3 channels/thread                 70.5 us  regress
//   R7  R2 + nt image loads — COMPILE FAIL (HIP_vector_type not accepted
//       by __builtin_nontemporal_load; needs clang ext_vector_type)
//   R8  (this) same as R7 with native vector type
//
// Model: counted HBM 2.55 TB/s; the rest of the 6.3 TB/s fabric is busy
// draining restore/poison dirty L3 lines during our window. FETCH=64 MiB of
// 128 MiB unique input => half the input is evicted before we read it.
// Read-once image lines are dead after load but MRU under LRU-ish L3
// replacement, so they displace the unread tail of d_in. nt loads mark them
// evict-first / no-allocate, protecting unread input + mask in L3.
// Stores stay NORMAL on purpose: a normal store merges into the poison's
// dirty L3 line in place (one eventual drain); an nt store would bypass and
// double the write drain (suspected cause of part of R4's regression).

constexpr int B  = 32;
constexpr int C  = 3;
constexpr int HW = 512 * 512;              // 262144 pixels per plane
constexpr int G_PER_PLANE = HW / 4;        // 65536 float4 groups (2^16)
constexpr int TOTAL_G = B * C * G_PER_PLANE;  // 6,291,456

// clang-native vector types (accepted by __builtin_nontemporal_load,
// identical 16-byte layout to HIP float4/int4)
typedef float nfloat4 __attribute__((ext_vector_type(4)));
typedef int   nint4   __attribute__((ext_vector_type(4)));

__global__ __launch_bounds__(256)
void sp_kernel(const float* __restrict__ img,
               const int*   __restrict__ mask,
               float*       __restrict__ out) {
    const int t = blockIdx.x * blockDim.x + threadIdx.x;  // one per out float4
    if (t >= TOTAL_G) return;

    const int plane = t >> 16;        // b*C + c, in [0, 96)
    const int b     = plane / 3;      // magic-mul, cheap
    const int g     = t & (G_PER_PLANE - 1);

    // mask: normal load (3x cross-channel reuse -> want L2/L3 retention)
    const nint4 m = *(const nint4*)(mask + (size_t)b * HW + (size_t)g * 4);

    // image: read-once stream -> nontemporal (evict-first, don't displace
    // the unread tail of d_in / mask lines from L3)
    const size_t off = (size_t)t * 4;   // linear over image/out
    const nfloat4 v = __builtin_nontemporal_load((const nfloat4*)(img + off));

    nfloat4 r;
    r.x = (m.x == 0) ? 0.0f : ((m.x == 1) ? 1.0f : v.x);
    r.y = (m.y == 0) ? 0.0f : ((m.y == 1) ? 1.0f : v.y);
    r.z = (m.z == 0) ? 0.0f : ((m.z == 1) ? 1.0f : v.z);
    r.w = (m.w == 0) ? 0.0f : ((m.w == 1) ? 1.0f : v.w);
    *(nfloat4*)(out + off) = r;       // normal store: merge into poison line
}

extern "C" void kernel_launch(void* const* d_in, const int* in_sizes, int n_in,
                              void* d_out, int out_size, void* d_ws, size_t ws_size,
                              hipStream_t stream) {
    const float* img  = (const float*)d_in[0];
    const int*   mask = (const int*)d_in[1];
    float*       out  = (float*)d_out;

    const int block = 256;
    const int grid  = TOTAL_G / block;   // 24576 blocks, exact
    sp_kernel<<<grid, block, 0, stream>>>(img, mask, out);
}